// Round 6
// baseline (4587.499 us; speedup 1.0000x reference)
//
#include <hip/hip_runtime.h>

#define TT 2048
#define SS 128
#define DMAXX 128
#define NBATCH 64

typedef float f2 __attribute__((ext_vector_type(2)));

__device__ __forceinline__ float fexp2(float x){ return __builtin_amdgcn_exp2f(x); }
__device__ __forceinline__ float flog2(float x){ return __builtin_amdgcn_logf(x); }
__device__ __forceinline__ float frcp (float x){ return __builtin_amdgcn_rcpf(x); }
__device__ __forceinline__ f2 pkfma(f2 a, f2 b, f2 c){ return __builtin_elementwise_fma(a, b, c); }

template<int CTRL>
__device__ __forceinline__ float dppf(float x) {
    int i = __float_as_int(x);
    return __int_as_float(__builtin_amdgcn_update_dpp(i, i, CTRL, 0xF, 0xF, false));
}
template<int CTRL>
__device__ __forceinline__ float dppzf(float x) {   // bound_ctrl: OOB source lanes read 0
    int i = __float_as_int(x);
    return __int_as_float(__builtin_amdgcn_update_dpp(0, i, CTRL, 0xF, 0xF, true));
}
#define DPP_XOR1   0xB1  // quad_perm(1,0,3,2)
#define DPP_XOR2   0x4E  // quad_perm(2,3,0,1)
#define DPP_RSHR4  0x114 // row_shr:4  (dst[s]=src[s-4] within 16-row, 0 for s<4)
#define DPP_ROR4   0x124
#define DPP_ROR8   0x128
#define DPP_BC15   0x142
#define DPP_BC31   0x143

constexpr float LOG2E = 1.4426950408889634f;
constexpr float LN2   = 0.6931471805599453f;

// R6 = R4/R5 with the VGPR clamp removed via explicit LLVM attributes:
//   amdgpu_flat_work_group_size(1024,1024) + amdgpu_waves_per_eu(4,4)
//   -> backend budget = 512-reg pool / 4 waves = 128 VGPR (state needs ~88).
//   __launch_bounds__(1024, {1,4}) both clamped to 64 VGPR -> full State
//   spill (WRITE_SIZE 5.9MB, 5.8x regression) in R4/R5 — theory untested
//   until now.
// TWO batches per 1024-thread block (16 waves = 4 waves/SIMD): sub-batch
//   bb = tid>>9 owns its own ua/wmax buffers.  The two sub-batches are
//   dataflow-independent chains; each SIMD carries one wave-pair from each,
//   so the ~500cy/step dependency-chain latency (ds_read + DPP links +
//   barrier) of one chain is filled by issue from the other.
// Within a sub-batch: identical to R2 (best measured): lane mapping
//   l = tid&63, w = (tid>>6)&7, r = l>>4, s = l&15, cc = l&3, q = (l>>2)&3,
//   state j = 16w + 4r + cc; lag-chunk q owns lags [32q+1..32q+32].
//   G-factored raw ring, tail-pipelined dur-sum, barrier at step bottom.
struct State {
    f2    rp[16];    // raw ring (entry/G at insert time)
    f2    eApk[16];  // eApk[cp*4+m] = (eA[8s+2m][j4+cp], eA[8s+2m+1][j4+cp])
    f2    eDp[32];   // pair table: eDp[w] = (eD[w], eD[(w+1)&31]) for (j, q)
    float eD0;       // exp(D[j][0])
    float pf[4];     // logB prefetch, distance 4
    const float* pfp;
    float C2;
    float e_pi;
    float G;         // cumulative scale within current 32-step rebase window
    float dsP;       // raw duration-sum for the upcoming step (from prev tail)
};

struct Ctx {
    const float4* up0; const float4* up1;  // U reads: 2 x float4 at group s
    const f2*     wmp;                     // renorm read pair
    float* uaw0; float* uaw1;              // U write (chunk-0 lanes)
    float* wmwp;                           // wave-max write (lane 63)
    bool q0, l63, b0, b1;                  // chunk0, lane63, l&1, l&2
};

template<int PHI>
__device__ __forceinline__ void hsmm_step(State& st, const Ctx& c, int tb)
{
    constexpr int  rho    = 31 - PHI;               // this step's fresh slot
    constexpr int  rhoN   = 31 - ((PHI + 1) & 31);  // slot to insert in the tail
    constexpr int  pb     = (PHI + 1) & 1;
    constexpr int  wb     = PHI & 1;
    constexpr bool DO_WM  = ((PHI & 7) == 6);
    constexpr bool DO_RN  = ((PHI & 7) == 7);
    constexpr bool REBASE = (PHI == 31);
    const int t = tb + PHI;

    // ---- U loads: 2 x b128 (8 floats), issued first ----
    const float4* up = pb ? c.up1 : c.up0;
    float4 va = up[0];
    float4 vb = up[1];

    // ---- step multiplier g and scale bookkeeping ----
    float xB = st.pf[PHI & 3];                 // logB[t]
    if (t + 4 < TT) st.pf[PHI & 3] = st.pfp[0];
    st.pfp += SS;
    float g = fexp2(xB * LOG2E);
    if constexpr (DO_RN) {
        f2 wv = *c.wmp;
        float m = fmaxf(wv.x, wv.y);
        m = fmaxf(m, dppf<DPP_XOR1>(m));
        m = fmaxf(m, dppf<DPP_XOR2>(m));       // max over all 8 waves (quad-combined)
        st.C2 += flog2(m);
        g *= frcp(m);
    }
    float rG = frcp(st.G);                     // 1/G_{t-1}
    float Gn = st.G * g;                       // G_t
    st.G = Gn;

    // ---- trans partials: 4 states of this row x 8 U values (16 pkfma, depth 4) ----
    f2 a0, a1, a2, a3, u;
    u = (f2){va.x, va.y};
    a0 = u * st.eApk[0];  a1 = u * st.eApk[4];  a2 = u * st.eApk[8];  a3 = u * st.eApk[12];
    u = (f2){va.z, va.w};
    a0 = pkfma(u, st.eApk[1], a0); a1 = pkfma(u, st.eApk[5], a1);
    a2 = pkfma(u, st.eApk[9], a2); a3 = pkfma(u, st.eApk[13], a3);
    u = (f2){vb.x, vb.y};
    a0 = pkfma(u, st.eApk[2], a0); a1 = pkfma(u, st.eApk[6], a1);
    a2 = pkfma(u, st.eApk[10], a2); a3 = pkfma(u, st.eApk[14], a3);
    u = (f2){vb.z, vb.w};
    a0 = pkfma(u, st.eApk[3], a0); a1 = pkfma(u, st.eApk[7], a1);
    a2 = pkfma(u, st.eApk[11], a2); a3 = pkfma(u, st.eApk[15], a3);

    // ---- quad butterfly transpose-reduce: lane ends with its OWN state (cc=l&3) ----
    float h0 = a0.x + a0.y, h1 = a1.x + a1.y, h2 = a2.x + a2.y, h3 = a3.x + a3.y;
    float s1 = c.b0 ? h0 : h1;                 // value sent to xor1 partner
    float k1 = c.b0 ? h1 : h0;                 // value kept
    float m01 = k1 + dppf<DPP_XOR1>(s1);       // pair-sum of h_{bit0}
    float s2 = c.b0 ? h2 : h3;
    float k2 = c.b0 ? h3 : h2;
    float m23 = k2 + dppf<DPP_XOR1>(s2);       // pair-sum of h_{2+bit0}
    float s3 = c.b1 ? m01 : m23;
    float k3 = c.b1 ? m23 : m01;
    float tp = k3 + dppf<DPP_XOR2>(s3);        // quad-sum of h_{l&3}
    tp += dppf<DPP_ROR4>(tp);
    tp += dppf<DPP_ROR8>(tp);                  // + other 3 quads of the row -> full Etrans[j]
    if constexpr (PHI == 0) { if (tb == 0) tp = st.e_pi; }   // t==0: entry = pi

    // ---- join: U = G*raw_dur(lags>=2) + fresh lag-1 term; patch fresh slot ----
    float U = fmaf(tp * g, st.eD0, st.dsP * Gn);
    if (c.q0) {
        float fr = tp * rG;                    // raw entry value = entry[t]/G_{t-1}
        if constexpr (rho & 1) st.rp[rho >> 1].y = fr;
        else                   st.rp[rho >> 1].x = fr;
        *(wb ? c.uaw1 : c.uaw0) = U;
    }

    // ---- wave max only on pre-renorm steps ----
    if constexpr (DO_WM) {
        float wm = U;
        wm = fmaxf(wm, dppf<DPP_XOR1>(wm));
        wm = fmaxf(wm, dppf<DPP_XOR2>(wm));    // quad = this row's 4 states -> row max
        wm = fmaxf(wm, dppf<DPP_BC15>(wm));
        wm = fmaxf(wm, dppf<DPP_BC31>(wm));
        if (c.l63) *c.wmwp = wm;
    }

    // ---- rebase once per 32-step window (fp32 range control) ----
    if constexpr (REBASE) {
        f2 GG = {Gn, Gn};
#pragma unroll
        for (int m2 = 0; m2 < 16; ++m2) st.rp[m2] = st.rp[m2] * GG;
        st.G = 1.f;
    }

    // ---- TAIL (pre-barrier, register-only): insert + raw dur-sum for step t+1 ----
    float rold;
    if constexpr (rhoN & 1) rold = st.rp[rhoN >> 1].y; else rold = st.rp[rhoN >> 1].x;
    float ins = dppzf<DPP_RSHR4>(rold);        // carry from chunk q-1; chunk0 lanes get 0
    if constexpr (rhoN & 1) st.rp[rhoN >> 1].y = ins;
    else                    st.rp[rhoN >> 1].x = ins;

    f2 q0a = {0.f, 0.f}, q1a = {0.f, 0.f}, q2a = {0.f, 0.f}, q3a = {0.f, 0.f};
#pragma unroll
    for (int m2 = 0; m2 < 16; m2 += 4) {
        q0a = pkfma(st.rp[m2],     st.eDp[(2 * m2 + PHI + 2) & 31], q0a);
        q1a = pkfma(st.rp[m2 + 1], st.eDp[(2 * m2 + PHI + 4) & 31], q1a);
        q2a = pkfma(st.rp[m2 + 2], st.eDp[(2 * m2 + PHI + 6) & 31], q2a);
        q3a = pkfma(st.rp[m2 + 3], st.eDp[(2 * m2 + PHI + 8) & 31], q3a);
    }
    f2 qs = (q0a + q1a) + (q2a + q3a);
    float ds = qs.x + qs.y;
    ds += dppf<DPP_ROR4>(ds);
    ds += dppf<DPP_ROR8>(ds);                  // sum over the 4 lag-chunk lanes (fixed cc)
    st.dsP = ds;

    asm volatile("s_waitcnt lgkmcnt(0)\n\ts_barrier" ::: "memory");
}

__attribute__((amdgpu_flat_work_group_size(1024, 1024)))
__attribute__((amdgpu_waves_per_eu(4, 4)))
__global__ void hsmm_fwd_kernel(const float* __restrict__ logB,
                                const float* __restrict__ pi,
                                const float* __restrict__ A,
                                const float* __restrict__ D,
                                float* __restrict__ out)
{
    const int tid  = threadIdx.x;
    const int bb   = tid >> 9;             // sub-batch within block (0/1)
    const int b    = blockIdx.x * 2 + bb;  // global batch
    const int l    = tid & 63;
    const int w    = (tid >> 6) & 7;       // wave within sub-batch
    const int r    = (l >> 4);
    const int sIdx = l & 15;
    const int cc   = l & 3;
    const int q    = (l >> 2) & 3;
    const int j4   = w * 16 + r * 4;
    const int j    = j4 + cc;

    // per-sub-batch U buffers: group s (U[8s..8s+8)) at float offset 12*s
    __shared__ __align__(16) float ua[2][2][16 * 12];
    __shared__ __align__(16) float wmaxf[2][8];

    State st;
#pragma unroll
    for (int cp = 0; cp < 4; ++cp)
#pragma unroll
        for (int m = 0; m < 4; ++m) {
            st.eApk[cp * 4 + m].x = fexp2(A[(8 * sIdx + 2 * m)     * SS + j4 + cp] * LOG2E);
            st.eApk[cp * 4 + m].y = fexp2(A[(8 * sIdx + 2 * m + 1) * SS + j4 + cp] * LOG2E);
        }
    {
        float eD[32];
#pragma unroll
        for (int k = 0; k < 32; ++k)
            eD[k] = fexp2(D[j * DMAXX + q * 32 + k] * LOG2E);
#pragma unroll
        for (int wdx = 0; wdx < 32; ++wdx) {
            st.eDp[wdx].x = eD[wdx];
            st.eDp[wdx].y = eD[(wdx + 1) & 31];
        }
    }
#pragma unroll
    for (int k = 0; k < 16; ++k) st.rp[k] = (f2){0.f, 0.f};
    st.eD0  = fexp2(D[j * DMAXX] * LOG2E);
    st.C2   = 0.f;
    st.e_pi = fexp2(pi[j] * LOG2E);
    st.G    = 1.f;
    st.dsP  = 0.f;

    const float* __restrict__ lb = logB + ((size_t)b * TT) * SS + j;
#pragma unroll
    for (int k = 0; k < 4; ++k) st.pf[k] = lb[(size_t)k * SS];
    st.pfp = lb + (size_t)4 * SS;

    Ctx c;
    c.up0  = (const float4*)&ua[bb][0][sIdx * 12];
    c.up1  = (const float4*)&ua[bb][1][sIdx * 12];
    c.wmp  = (const f2*)&wmaxf[bb][2 * cc];
    c.q0   = (q == 0);
    c.l63  = (l == 63);
    c.b0   = (l & 1);
    c.b1   = ((l & 2) != 0);
    c.uaw0 = &ua[bb][0][(j >> 3) * 12 + (j & 7)];
    c.uaw1 = &ua[bb][1][(j >> 3) * 12 + (j & 7)];
    c.wmwp = &wmaxf[bb][w];

    for (int tb = 0; tb < TT; tb += 32) {
        hsmm_step< 0>(st, c, tb); hsmm_step< 1>(st, c, tb);
        hsmm_step< 2>(st, c, tb); hsmm_step< 3>(st, c, tb);
        hsmm_step< 4>(st, c, tb); hsmm_step< 5>(st, c, tb);
        hsmm_step< 6>(st, c, tb); hsmm_step< 7>(st, c, tb);
        hsmm_step< 8>(st, c, tb); hsmm_step< 9>(st, c, tb);
        hsmm_step<10>(st, c, tb); hsmm_step<11>(st, c, tb);
        hsmm_step<12>(st, c, tb); hsmm_step<13>(st, c, tb);
        hsmm_step<14>(st, c, tb); hsmm_step<15>(st, c, tb);
        hsmm_step<16>(st, c, tb); hsmm_step<17>(st, c, tb);
        hsmm_step<18>(st, c, tb); hsmm_step<19>(st, c, tb);
        hsmm_step<20>(st, c, tb); hsmm_step<21>(st, c, tb);
        hsmm_step<22>(st, c, tb); hsmm_step<23>(st, c, tb);
        hsmm_step<24>(st, c, tb); hsmm_step<25>(st, c, tb);
        hsmm_step<26>(st, c, tb); hsmm_step<27>(st, c, tb);
        hsmm_step<28>(st, c, tb); hsmm_step<29>(st, c, tb);
        hsmm_step<30>(st, c, tb); hsmm_step<31>(st, c, tb);
    }

    // epilogue: out[b] = (C2 + log2(sum_j U_{T-1}[j])) * ln2 ;  (T-1)&1 == 1
    if (l == 0 && w == 0) {
        float s = 0.f;
        for (int i = 0; i < SS; ++i) s += ua[bb][1][(i >> 3) * 12 + (i & 7)];
        out[b] = (st.C2 + flog2(s)) * LN2;
    }
}

extern "C" void kernel_launch(void* const* d_in, const int* in_sizes, int n_in,
                              void* d_out, int out_size, void* d_ws, size_t ws_size,
                              hipStream_t stream) {
    const float* logB = (const float*)d_in[0];   // (64, 2048, 128) f32
    const float* pi   = (const float*)d_in[1];   // (128,) f32
    const float* A    = (const float*)d_in[2];   // (128, 128) f32
    const float* D    = (const float*)d_in[3];   // (128, 128) f32
    float* out        = (float*)d_out;           // (64,) f32
    hipLaunchKernelGGL(hsmm_fwd_kernel, dim3(NBATCH / 2), dim3(1024), 0, stream,
                       logB, pi, A, D, out);
}

// Round 7
// 841.152 us; speedup vs baseline: 5.4538x; 5.4538x over previous
//
#include <hip/hip_runtime.h>

#define TT 2048
#define SS 128
#define DMAXX 128
#define NBATCH 64

typedef float f2 __attribute__((ext_vector_type(2)));

__device__ __forceinline__ float fexp2(float x){ return __builtin_amdgcn_exp2f(x); }
__device__ __forceinline__ float flog2(float x){ return __builtin_amdgcn_logf(x); }
__device__ __forceinline__ float frcp (float x){ return __builtin_amdgcn_rcpf(x); }
__device__ __forceinline__ f2 pkfma(f2 a, f2 b, f2 c){ return __builtin_elementwise_fma(a, b, c); }

template<int CTRL>
__device__ __forceinline__ float dppf(float x) {
    int i = __float_as_int(x);
    return __int_as_float(__builtin_amdgcn_update_dpp(i, i, CTRL, 0xF, 0xF, false));
}
template<int CTRL>
__device__ __forceinline__ float dppzf(float x) {   // bound_ctrl: OOB source lanes read 0
    int i = __float_as_int(x);
    return __int_as_float(__builtin_amdgcn_update_dpp(0, i, CTRL, 0xF, 0xF, true));
}
#define DPP_XOR1   0xB1  // quad_perm(1,0,3,2)
#define DPP_XOR2   0x4E  // quad_perm(2,3,0,1)
#define DPP_RSHR4  0x114 // row_shr:4  (dst[s]=src[s-4] within 16-row, 0 for s<4)
#define DPP_ROR4   0x124
#define DPP_ROR8   0x128
#define DPP_BC15   0x142
#define DPP_BC31   0x143

constexpr float LOG2E = 1.4426950408889634f;
constexpr float LN2   = 0.6931471805599453f;

// R7 = R2 (measured best, 781us) + deep logB prefetch.
//   1024-thread routes (R4-R6) are dead: toolchain hard-clamps 64 VGPR for
//   1024-thread workgroups -> full State spill.  Reverted to 512 threads.
//   Change vs R2: logB prefetch distance 4 -> 8 (pf[8], PHI&7 rotation),
//   loads use compile-time offset immediates ((PHI&7)*SS*4 <= 3584B fits the
//   13-bit signed field), prefetch pointer advances once per 8 steps.
//   Purpose: if the ~500cy/step unexplained wall is HBM/L2 load-latency
//   leaking past the distance-4 pipeline (FETCH=33MB -> logB is NOT
//   L3-resident), depth-8 removes it.  Null result rules memory out.
// Lane mapping (R2): l = tid&63, w = tid>>6, r = l>>4, s = l&15, cc = l&3,
//   q = (l>>2)&3.   State j = 16w + 4r + cc;  lag-chunk q owns lags [32q+1..32q+32].
//   G-factored raw ring, tail-pipelined dur-sum, barrier at step bottom.
struct State {
    f2    rp[16];    // raw ring (entry/G at insert time)
    f2    eApk[16];  // eApk[cp*4+m] = (eA[8s+2m][j4+cp], eA[8s+2m+1][j4+cp])
    f2    eDp[32];   // pair table: eDp[w] = (eD[w], eD[(w+1)&31]) for (j, q)
    float eD0;       // exp(D[j][0])
    float pf[8];     // logB prefetch, distance 8
    const float* pfp;  // = lb + (tb+8)*SS at the start of each 8-step group
    float C2;
    float e_pi;
    float G;         // cumulative scale within current 32-step rebase window
    float dsP;       // raw duration-sum for the upcoming step (from prev tail)
};

struct Ctx {
    const float4* up0; const float4* up1;  // U reads: 2 x float4 at group s
    const f2*     wmp;                     // renorm read pair
    float* uaw0; float* uaw1;              // U write (chunk-0 lanes)
    float* wmwp;                           // wave-max write (lane 63)
    bool q0, l63, b0, b1;                  // chunk0, lane63, l&1, l&2
};

template<int PHI>
__device__ __forceinline__ void hsmm_step(State& st, const Ctx& c, int tb)
{
    constexpr int  rho    = 31 - PHI;               // this step's fresh slot
    constexpr int  rhoN   = 31 - ((PHI + 1) & 31);  // slot to insert in the tail
    constexpr int  pb     = (PHI + 1) & 1;
    constexpr int  wb     = PHI & 1;
    constexpr bool DO_WM  = ((PHI & 7) == 6);
    constexpr bool DO_RN  = ((PHI & 7) == 7);
    constexpr bool REBASE = (PHI == 31);
    const int t = tb + PHI;

    // ---- U loads: 2 x b128 (8 floats), issued first ----
    const float4* up = pb ? c.up1 : c.up0;
    float4 va = up[0];
    float4 vb = up[1];

    // ---- logB: consume depth-8 prefetch, issue replacement with imm offset ----
    float xB = st.pf[PHI & 7];                 // logB[t], loaded 8 steps ago
    if (t + 8 < TT) st.pf[PHI & 7] = st.pfp[(PHI & 7) * SS];
    if constexpr ((PHI & 7) == 7) st.pfp += 8 * SS;

    // ---- step multiplier g and scale bookkeeping ----
    float g = fexp2(xB * LOG2E);
    if constexpr (DO_RN) {
        f2 wv = *c.wmp;
        float m = fmaxf(wv.x, wv.y);
        m = fmaxf(m, dppf<DPP_XOR1>(m));
        m = fmaxf(m, dppf<DPP_XOR2>(m));       // max over all 8 waves (quad-combined)
        st.C2 += flog2(m);
        g *= frcp(m);
    }
    float rG = frcp(st.G);                     // 1/G_{t-1}
    float Gn = st.G * g;                       // G_t
    st.G = Gn;

    // ---- trans partials: 4 states of this row x 8 U values (16 pkfma, depth 4) ----
    f2 a0, a1, a2, a3, u;
    u = (f2){va.x, va.y};
    a0 = u * st.eApk[0];  a1 = u * st.eApk[4];  a2 = u * st.eApk[8];  a3 = u * st.eApk[12];
    u = (f2){va.z, va.w};
    a0 = pkfma(u, st.eApk[1], a0); a1 = pkfma(u, st.eApk[5], a1);
    a2 = pkfma(u, st.eApk[9], a2); a3 = pkfma(u, st.eApk[13], a3);
    u = (f2){vb.x, vb.y};
    a0 = pkfma(u, st.eApk[2], a0); a1 = pkfma(u, st.eApk[6], a1);
    a2 = pkfma(u, st.eApk[10], a2); a3 = pkfma(u, st.eApk[14], a3);
    u = (f2){vb.z, vb.w};
    a0 = pkfma(u, st.eApk[3], a0); a1 = pkfma(u, st.eApk[7], a1);
    a2 = pkfma(u, st.eApk[11], a2); a3 = pkfma(u, st.eApk[15], a3);

    // ---- quad butterfly transpose-reduce: lane ends with its OWN state (cc=l&3) ----
    float h0 = a0.x + a0.y, h1 = a1.x + a1.y, h2 = a2.x + a2.y, h3 = a3.x + a3.y;
    float s1 = c.b0 ? h0 : h1;                 // value sent to xor1 partner
    float k1 = c.b0 ? h1 : h0;                 // value kept
    float m01 = k1 + dppf<DPP_XOR1>(s1);       // pair-sum of h_{bit0}
    float s2 = c.b0 ? h2 : h3;
    float k2 = c.b0 ? h3 : h2;
    float m23 = k2 + dppf<DPP_XOR1>(s2);       // pair-sum of h_{2+bit0}
    float s3 = c.b1 ? m01 : m23;
    float k3 = c.b1 ? m23 : m01;
    float tp = k3 + dppf<DPP_XOR2>(s3);        // quad-sum of h_{l&3}
    tp += dppf<DPP_ROR4>(tp);
    tp += dppf<DPP_ROR8>(tp);                  // + other 3 quads of the row -> full Etrans[j]
    if constexpr (PHI == 0) { if (tb == 0) tp = st.e_pi; }   // t==0: entry = pi

    // ---- join: U = G*raw_dur(lags>=2) + fresh lag-1 term; patch fresh slot ----
    float U = fmaf(tp * g, st.eD0, st.dsP * Gn);
    if (c.q0) {
        float fr = tp * rG;                    // raw entry value = entry[t]/G_{t-1}
        if constexpr (rho & 1) st.rp[rho >> 1].y = fr;
        else                   st.rp[rho >> 1].x = fr;
        *(wb ? c.uaw1 : c.uaw0) = U;
    }

    // ---- wave max only on pre-renorm steps ----
    if constexpr (DO_WM) {
        float wm = U;
        wm = fmaxf(wm, dppf<DPP_XOR1>(wm));
        wm = fmaxf(wm, dppf<DPP_XOR2>(wm));    // quad = this row's 4 states -> row max
        wm = fmaxf(wm, dppf<DPP_BC15>(wm));
        wm = fmaxf(wm, dppf<DPP_BC31>(wm));
        if (c.l63) *c.wmwp = wm;
    }

    // ---- rebase once per 32-step window (fp32 range control) ----
    if constexpr (REBASE) {
        f2 GG = {Gn, Gn};
#pragma unroll
        for (int m2 = 0; m2 < 16; ++m2) st.rp[m2] = st.rp[m2] * GG;
        st.G = 1.f;
    }

    // ---- TAIL (pre-barrier, register-only): insert + raw dur-sum for step t+1 ----
    float rold;
    if constexpr (rhoN & 1) rold = st.rp[rhoN >> 1].y; else rold = st.rp[rhoN >> 1].x;
    float ins = dppzf<DPP_RSHR4>(rold);        // carry from chunk q-1; chunk0 lanes get 0
    if constexpr (rhoN & 1) st.rp[rhoN >> 1].y = ins;
    else                    st.rp[rhoN >> 1].x = ins;

    f2 q0a = {0.f, 0.f}, q1a = {0.f, 0.f}, q2a = {0.f, 0.f}, q3a = {0.f, 0.f};
#pragma unroll
    for (int m2 = 0; m2 < 16; m2 += 4) {
        q0a = pkfma(st.rp[m2],     st.eDp[(2 * m2 + PHI + 2) & 31], q0a);
        q1a = pkfma(st.rp[m2 + 1], st.eDp[(2 * m2 + PHI + 4) & 31], q1a);
        q2a = pkfma(st.rp[m2 + 2], st.eDp[(2 * m2 + PHI + 6) & 31], q2a);
        q3a = pkfma(st.rp[m2 + 3], st.eDp[(2 * m2 + PHI + 8) & 31], q3a);
    }
    f2 qs = (q0a + q1a) + (q2a + q3a);
    float ds = qs.x + qs.y;
    ds += dppf<DPP_ROR4>(ds);
    ds += dppf<DPP_ROR8>(ds);                  // sum over the 4 lag-chunk lanes (fixed cc)
    st.dsP = ds;

    asm volatile("s_waitcnt lgkmcnt(0)\n\ts_barrier" ::: "memory");
}

__launch_bounds__(512, 2)
__global__ void hsmm_fwd_kernel(const float* __restrict__ logB,
                                const float* __restrict__ pi,
                                const float* __restrict__ A,
                                const float* __restrict__ D,
                                float* __restrict__ out)
{
    const int b    = blockIdx.x;
    const int tid  = threadIdx.x;
    const int l    = tid & 63;
    const int w    = tid >> 6;
    const int r    = (l >> 4);
    const int sIdx = l & 15;
    const int cc   = l & 3;
    const int q    = (l >> 2) & 3;
    const int j4   = w * 16 + r * 4;
    const int j    = j4 + cc;

    // U groups: group s (U[8s..8s+8)) at float offset 12*s (2-way bank alias = free)
    __shared__ __align__(16) float ua[2][16 * 12];
    __shared__ __align__(16) float wmaxf[8];

    State st;
#pragma unroll
    for (int cp = 0; cp < 4; ++cp)
#pragma unroll
        for (int m = 0; m < 4; ++m) {
            st.eApk[cp * 4 + m].x = fexp2(A[(8 * sIdx + 2 * m)     * SS + j4 + cp] * LOG2E);
            st.eApk[cp * 4 + m].y = fexp2(A[(8 * sIdx + 2 * m + 1) * SS + j4 + cp] * LOG2E);
        }
    {
        float eD[32];
#pragma unroll
        for (int k = 0; k < 32; ++k)
            eD[k] = fexp2(D[j * DMAXX + q * 32 + k] * LOG2E);
#pragma unroll
        for (int wdx = 0; wdx < 32; ++wdx) {
            st.eDp[wdx].x = eD[wdx];
            st.eDp[wdx].y = eD[(wdx + 1) & 31];
        }
    }
#pragma unroll
    for (int k = 0; k < 16; ++k) st.rp[k] = (f2){0.f, 0.f};
    st.eD0  = fexp2(D[j * DMAXX] * LOG2E);
    st.C2   = 0.f;
    st.e_pi = fexp2(pi[j] * LOG2E);
    st.G    = 1.f;
    st.dsP  = 0.f;

    const float* __restrict__ lb = logB + ((size_t)b * TT) * SS + j;
#pragma unroll
    for (int k = 0; k < 8; ++k) st.pf[k] = lb[(size_t)k * SS];
    st.pfp = lb + (size_t)8 * SS;

    Ctx c;
    c.up0  = (const float4*)&ua[0][sIdx * 12];
    c.up1  = (const float4*)&ua[1][sIdx * 12];
    c.wmp  = (const f2*)&wmaxf[2 * cc];
    c.q0   = (q == 0);
    c.l63  = (l == 63);
    c.b0   = (l & 1);
    c.b1   = ((l & 2) != 0);
    c.uaw0 = &ua[0][(j >> 3) * 12 + (j & 7)];
    c.uaw1 = &ua[1][(j >> 3) * 12 + (j & 7)];
    c.wmwp = &wmaxf[w];

    for (int tb = 0; tb < TT; tb += 32) {
        hsmm_step< 0>(st, c, tb); hsmm_step< 1>(st, c, tb);
        hsmm_step< 2>(st, c, tb); hsmm_step< 3>(st, c, tb);
        hsmm_step< 4>(st, c, tb); hsmm_step< 5>(st, c, tb);
        hsmm_step< 6>(st, c, tb); hsmm_step< 7>(st, c, tb);
        hsmm_step< 8>(st, c, tb); hsmm_step< 9>(st, c, tb);
        hsmm_step<10>(st, c, tb); hsmm_step<11>(st, c, tb);
        hsmm_step<12>(st, c, tb); hsmm_step<13>(st, c, tb);
        hsmm_step<14>(st, c, tb); hsmm_step<15>(st, c, tb);
        hsmm_step<16>(st, c, tb); hsmm_step<17>(st, c, tb);
        hsmm_step<18>(st, c, tb); hsmm_step<19>(st, c, tb);
        hsmm_step<20>(st, c, tb); hsmm_step<21>(st, c, tb);
        hsmm_step<22>(st, c, tb); hsmm_step<23>(st, c, tb);
        hsmm_step<24>(st, c, tb); hsmm_step<25>(st, c, tb);
        hsmm_step<26>(st, c, tb); hsmm_step<27>(st, c, tb);
        hsmm_step<28>(st, c, tb); hsmm_step<29>(st, c, tb);
        hsmm_step<30>(st, c, tb); hsmm_step<31>(st, c, tb);
    }

    // epilogue: out[b] = (C2 + log2(sum_j U_{T-1}[j])) * ln2 ;  (T-1)&1 == 1
    if (tid == 0) {
        float s = 0.f;
        for (int i = 0; i < SS; ++i) s += ua[1][(i >> 3) * 12 + (i & 7)];
        out[b] = (st.C2 + flog2(s)) * LN2;
    }
}

extern "C" void kernel_launch(void* const* d_in, const int* in_sizes, int n_in,
                              void* d_out, int out_size, void* d_ws, size_t ws_size,
                              hipStream_t stream) {
    const float* logB = (const float*)d_in[0];   // (64, 2048, 128) f32
    const float* pi   = (const float*)d_in[1];   // (128,) f32
    const float* A    = (const float*)d_in[2];   // (128, 128) f32
    const float* D    = (const float*)d_in[3];   // (128, 128) f32
    float* out        = (float*)d_out;           // (64,) f32
    hipLaunchKernelGGL(hsmm_fwd_kernel, dim3(NBATCH), dim3(512), 0, stream,
                       logB, pi, A, D, out);
}

// Round 8
// 825.454 us; speedup vs baseline: 5.5575x; 1.0190x over previous
//
#include <hip/hip_runtime.h>

#define TT 2048
#define SS 128
#define DMAXX 128
#define NBATCH 64

typedef float f2 __attribute__((ext_vector_type(2)));

__device__ __forceinline__ float fexp2(float x){ return __builtin_amdgcn_exp2f(x); }
__device__ __forceinline__ float flog2(float x){ return __builtin_amdgcn_logf(x); }
__device__ __forceinline__ float frcp (float x){ return __builtin_amdgcn_rcpf(x); }
__device__ __forceinline__ f2 pkfma(f2 a, f2 b, f2 c){ return __builtin_elementwise_fma(a, b, c); }

template<int CTRL>
__device__ __forceinline__ float dppf(float x) {
    int i = __float_as_int(x);
    return __int_as_float(__builtin_amdgcn_update_dpp(i, i, CTRL, 0xF, 0xF, false));
}
template<int CTRL>
__device__ __forceinline__ float dppzf(float x) {   // bound_ctrl: OOB source lanes read 0
    int i = __float_as_int(x);
    return __int_as_float(__builtin_amdgcn_update_dpp(0, i, CTRL, 0xF, 0xF, true));
}
#define DPP_XOR1   0xB1  // quad_perm(1,0,3,2)
#define DPP_XOR2   0x4E  // quad_perm(2,3,0,1)
#define DPP_RSHR4  0x114 // row_shr:4  (dst[s]=src[s-4] within 16-row, 0 for s<4)
#define DPP_ROR4   0x124
#define DPP_ROR8   0x128
#define DPP_BC15   0x142
#define DPP_BC31   0x143

constexpr float LOG2E = 1.4426950408889634f;
constexpr float LN2   = 0.6931471805599453f;

// R8 = R2's math, modulo-scheduled into an 8-STEP LOOP BODY (~6KB) instead of
// the 32-step full unroll (~23KB).  Hypothesis: the ~600cy/step residual wall
// (insensitive to reordering R3, data prefetch R7, VALU-count R1->R2) is
// I-cache thrash of the 23KB body streaming from L2 every iteration.
//
// Frame rotation: at block k (steps 8k..8k+7), ring reg r holds slot
// (r - 8k) mod 32.  Then: insert reg = 31-p; tail insert reg = 30-p; and in
// every eDp pairing (slot + PHI + c) the 8k cancels -> (2m2 + p + c)&31.
// eApk/eDp stay STATIC; only rp is cyclically shifted by 4 f2 regs per block
// (new[(i+4)&15] = old[i], 32 v_mov / 8 steps).  Rebase moved to every block
// end (p=7; stricter fp-range control, same semantics).  WM/RN already
// period-8.  #pragma unroll 1 pins the rolled loop.
// Lane mapping (R2): l=tid&63, w=tid>>6, r=l>>4, s=l&15, cc=l&3, q=(l>>2)&3.
// State j = 16w+4r+cc; lag-chunk q owns lags [32q+1..32q+32].
// G-factored raw ring, tail-pipelined dur-sum, barrier at step bottom.
struct State {
    f2    rp[16];    // raw ring (rotating frame)
    f2    eApk[16];  // eApk[cp*4+m] = (eA[8s+2m][j4+cp], eA[8s+2m+1][j4+cp])
    f2    eDp[32];   // pair table: eDp[w] = (eD[w], eD[(w+1)&31]) for (j, q)
    float eD0;       // exp(D[j][0])
    float pf[4];     // logB prefetch, distance 4
    const float* pfp;  // = lb + (tb8+4)*SS at block start
    float C2;
    float e_pi;
    float G;         // cumulative scale within current 8-step rebase window
    float dsP;       // raw duration-sum for the upcoming step (from prev tail)
};

struct Ctx {
    const float4* up0; const float4* up1;  // U reads: 2 x float4 at group s
    const f2*     wmp;                     // renorm read pair
    float* uaw0; float* uaw1;              // U write (chunk-0 lanes)
    float* wmwp;                           // wave-max write (lane 63)
    bool q0, l63, b0, b1;                  // chunk0, lane63, l&1, l&2
};

template<int P>
__device__ __forceinline__ void hsmm_step(State& st, const Ctx& c, int tb8)
{
    constexpr int  rho    = 31 - P;        // this step's fresh slot (frame reg)
    constexpr int  rhoN   = 30 - P;        // tail insert reg (P=7 -> 23, moves to 31 on rotate)
    constexpr int  pb     = (P + 1) & 1;
    constexpr int  wb     = P & 1;
    constexpr bool DO_WM  = (P == 6);
    constexpr bool DO_RN  = (P == 7);
    constexpr bool REBASE = (P == 7);
    const int t = tb8 + P;

    // ---- U loads: 2 x b128 (8 floats), issued first ----
    const float4* up = pb ? c.up1 : c.up0;
    float4 va = up[0];
    float4 vb = up[1];

    // ---- logB: consume depth-4 prefetch, refill with imm-offset load ----
    float xB = st.pf[P & 3];               // logB[t], loaded 4 steps ago
    if (t + 4 < TT) st.pf[P & 3] = st.pfp[P * SS];
    if constexpr (P == 7) st.pfp += 8 * SS;

    // ---- step multiplier g and scale bookkeeping ----
    float g = fexp2(xB * LOG2E);
    if constexpr (DO_RN) {
        f2 wv = *c.wmp;
        float m = fmaxf(wv.x, wv.y);
        m = fmaxf(m, dppf<DPP_XOR1>(m));
        m = fmaxf(m, dppf<DPP_XOR2>(m));   // max over all 8 waves (quad-combined)
        st.C2 += flog2(m);
        g *= frcp(m);
    }
    float rG = frcp(st.G);                 // 1/G_{t-1}
    float Gn = st.G * g;                   // G_t
    st.G = Gn;

    // ---- trans partials: 4 states of this row x 8 U values (16 pkfma, depth 4) ----
    f2 a0, a1, a2, a3, u;
    u = (f2){va.x, va.y};
    a0 = u * st.eApk[0];  a1 = u * st.eApk[4];  a2 = u * st.eApk[8];  a3 = u * st.eApk[12];
    u = (f2){va.z, va.w};
    a0 = pkfma(u, st.eApk[1], a0); a1 = pkfma(u, st.eApk[5], a1);
    a2 = pkfma(u, st.eApk[9], a2); a3 = pkfma(u, st.eApk[13], a3);
    u = (f2){vb.x, vb.y};
    a0 = pkfma(u, st.eApk[2], a0); a1 = pkfma(u, st.eApk[6], a1);
    a2 = pkfma(u, st.eApk[10], a2); a3 = pkfma(u, st.eApk[14], a3);
    u = (f2){vb.z, vb.w};
    a0 = pkfma(u, st.eApk[3], a0); a1 = pkfma(u, st.eApk[7], a1);
    a2 = pkfma(u, st.eApk[11], a2); a3 = pkfma(u, st.eApk[15], a3);

    // ---- quad butterfly transpose-reduce: lane ends with its OWN state (cc=l&3) ----
    float h0 = a0.x + a0.y, h1 = a1.x + a1.y, h2 = a2.x + a2.y, h3 = a3.x + a3.y;
    float s1 = c.b0 ? h0 : h1;
    float k1 = c.b0 ? h1 : h0;
    float m01 = k1 + dppf<DPP_XOR1>(s1);
    float s2 = c.b0 ? h2 : h3;
    float k2 = c.b0 ? h3 : h2;
    float m23 = k2 + dppf<DPP_XOR1>(s2);
    float s3 = c.b1 ? m01 : m23;
    float k3 = c.b1 ? m23 : m01;
    float tp = k3 + dppf<DPP_XOR2>(s3);    // quad-sum of h_{l&3}
    tp += dppf<DPP_ROR4>(tp);
    tp += dppf<DPP_ROR8>(tp);              // full Etrans[j]
    if constexpr (P == 0) { if (tb8 == 0) tp = st.e_pi; }   // t==0: entry = pi

    // ---- join: U = G*raw_dur(lags>=2) + fresh lag-1 term; patch fresh slot ----
    float U = fmaf(tp * g, st.eD0, st.dsP * Gn);
    if (c.q0) {
        float fr = tp * rG;                // raw entry value = entry[t]/G_{t-1}
        if constexpr (rho & 1) st.rp[rho >> 1].y = fr;
        else                   st.rp[rho >> 1].x = fr;
        *(wb ? c.uaw1 : c.uaw0) = U;
    }

    // ---- wave max only on pre-renorm steps ----
    if constexpr (DO_WM) {
        float wm = U;
        wm = fmaxf(wm, dppf<DPP_XOR1>(wm));
        wm = fmaxf(wm, dppf<DPP_XOR2>(wm));
        wm = fmaxf(wm, dppf<DPP_BC15>(wm));
        wm = fmaxf(wm, dppf<DPP_BC31>(wm));
        if (c.l63) *c.wmwp = wm;
    }

    // ---- rebase once per 8-step block (fp32 range control) ----
    if constexpr (REBASE) {
        f2 GG = {Gn, Gn};
#pragma unroll
        for (int m2 = 0; m2 < 16; ++m2) st.rp[m2] = st.rp[m2] * GG;
        st.G = 1.f;
    }

    // ---- TAIL (pre-barrier, register-only): insert + raw dur-sum for step t+1 ----
    float rold;
    if constexpr (rhoN & 1) rold = st.rp[rhoN >> 1].y; else rold = st.rp[rhoN >> 1].x;
    float ins = dppzf<DPP_RSHR4>(rold);    // carry from chunk q-1; chunk0 lanes get 0
    if constexpr (rhoN & 1) st.rp[rhoN >> 1].y = ins;
    else                    st.rp[rhoN >> 1].x = ins;

    f2 q0a = {0.f, 0.f}, q1a = {0.f, 0.f}, q2a = {0.f, 0.f}, q3a = {0.f, 0.f};
#pragma unroll
    for (int m2 = 0; m2 < 16; m2 += 4) {
        q0a = pkfma(st.rp[m2],     st.eDp[(2 * m2 + P + 2) & 31], q0a);
        q1a = pkfma(st.rp[m2 + 1], st.eDp[(2 * m2 + P + 4) & 31], q1a);
        q2a = pkfma(st.rp[m2 + 2], st.eDp[(2 * m2 + P + 6) & 31], q2a);
        q3a = pkfma(st.rp[m2 + 3], st.eDp[(2 * m2 + P + 8) & 31], q3a);
    }
    f2 qs = (q0a + q1a) + (q2a + q3a);
    float ds = qs.x + qs.y;
    ds += dppf<DPP_ROR4>(ds);
    ds += dppf<DPP_ROR8>(ds);              // sum over the 4 lag-chunk lanes (fixed cc)
    st.dsP = ds;

    asm volatile("s_waitcnt lgkmcnt(0)\n\ts_barrier" ::: "memory");
}

__launch_bounds__(512, 2)
__global__ void hsmm_fwd_kernel(const float* __restrict__ logB,
                                const float* __restrict__ pi,
                                const float* __restrict__ A,
                                const float* __restrict__ D,
                                float* __restrict__ out)
{
    const int b    = blockIdx.x;
    const int tid  = threadIdx.x;
    const int l    = tid & 63;
    const int w    = tid >> 6;
    const int r    = (l >> 4);
    const int sIdx = l & 15;
    const int cc   = l & 3;
    const int q    = (l >> 2) & 3;
    const int j4   = w * 16 + r * 4;
    const int j    = j4 + cc;

    // U groups: group s (U[8s..8s+8)) at float offset 12*s (2-way bank alias = free)
    __shared__ __align__(16) float ua[2][16 * 12];
    __shared__ __align__(16) float wmaxf[8];

    State st;
#pragma unroll
    for (int cp = 0; cp < 4; ++cp)
#pragma unroll
        for (int m = 0; m < 4; ++m) {
            st.eApk[cp * 4 + m].x = fexp2(A[(8 * sIdx + 2 * m)     * SS + j4 + cp] * LOG2E);
            st.eApk[cp * 4 + m].y = fexp2(A[(8 * sIdx + 2 * m + 1) * SS + j4 + cp] * LOG2E);
        }
    {
        float eD[32];
#pragma unroll
        for (int k = 0; k < 32; ++k)
            eD[k] = fexp2(D[j * DMAXX + q * 32 + k] * LOG2E);
#pragma unroll
        for (int wdx = 0; wdx < 32; ++wdx) {
            st.eDp[wdx].x = eD[wdx];
            st.eDp[wdx].y = eD[(wdx + 1) & 31];
        }
    }
#pragma unroll
    for (int k = 0; k < 16; ++k) st.rp[k] = (f2){0.f, 0.f};
    st.eD0  = fexp2(D[j * DMAXX] * LOG2E);
    st.C2   = 0.f;
    st.e_pi = fexp2(pi[j] * LOG2E);
    st.G    = 1.f;
    st.dsP  = 0.f;

    const float* __restrict__ lb = logB + ((size_t)b * TT) * SS + j;
#pragma unroll
    for (int k = 0; k < 4; ++k) st.pf[k] = lb[(size_t)k * SS];
    st.pfp = lb + (size_t)4 * SS;

    Ctx c;
    c.up0  = (const float4*)&ua[0][sIdx * 12];
    c.up1  = (const float4*)&ua[1][sIdx * 12];
    c.wmp  = (const f2*)&wmaxf[2 * cc];
    c.q0   = (q == 0);
    c.l63  = (l == 63);
    c.b0   = (l & 1);
    c.b1   = ((l & 2) != 0);
    c.uaw0 = &ua[0][(j >> 3) * 12 + (j & 7)];
    c.uaw1 = &ua[1][(j >> 3) * 12 + (j & 7)];
    c.wmwp = &wmaxf[w];

#pragma unroll 1
    for (int tb8 = 0; tb8 < TT; tb8 += 8) {
        hsmm_step<0>(st, c, tb8); hsmm_step<1>(st, c, tb8);
        hsmm_step<2>(st, c, tb8); hsmm_step<3>(st, c, tb8);
        hsmm_step<4>(st, c, tb8); hsmm_step<5>(st, c, tb8);
        hsmm_step<6>(st, c, tb8); hsmm_step<7>(st, c, tb8);
        // ---- frame rotation: new[(i+4)&15] = old[i]  (shift ring by 8 slots) ----
        {
            f2 t12 = st.rp[12], t13 = st.rp[13], t14 = st.rp[14], t15 = st.rp[15];
            st.rp[15] = st.rp[11]; st.rp[14] = st.rp[10];
            st.rp[13] = st.rp[9];  st.rp[12] = st.rp[8];
            st.rp[11] = st.rp[7];  st.rp[10] = st.rp[6];
            st.rp[9]  = st.rp[5];  st.rp[8]  = st.rp[4];
            st.rp[7]  = st.rp[3];  st.rp[6]  = st.rp[2];
            st.rp[5]  = st.rp[1];  st.rp[4]  = st.rp[0];
            st.rp[3] = t15; st.rp[2] = t14; st.rp[1] = t13; st.rp[0] = t12;
        }
    }

    // epilogue: out[b] = (C2 + log2(sum_j U_{T-1}[j])) * ln2 ;  (T-1)&1 == 1
    if (tid == 0) {
        float s = 0.f;
        for (int i = 0; i < SS; ++i) s += ua[1][(i >> 3) * 12 + (i & 7)];
        out[b] = (st.C2 + flog2(s)) * LN2;
    }
}

extern "C" void kernel_launch(void* const* d_in, const int* in_sizes, int n_in,
                              void* d_out, int out_size, void* d_ws, size_t ws_size,
                              hipStream_t stream) {
    const float* logB = (const float*)d_in[0];   // (64, 2048, 128) f32
    const float* pi   = (const float*)d_in[1];   // (128,) f32
    const float* A    = (const float*)d_in[2];   // (128, 128) f32
    const float* D    = (const float*)d_in[3];   // (128, 128) f32
    float* out        = (float*)d_out;           // (64,) f32
    hipLaunchKernelGGL(hsmm_fwd_kernel, dim3(NBATCH), dim3(512), 0, stream,
                       logB, pi, A, D, out);
}